// Round 3
// baseline (449.333 us; speedup 1.0000x reference)
//
#include <hip/hip_runtime.h>

// out = x + alpha * softmax(beta * x @ K^T) @ V   (B=4096, N=16384, D=1024, fp32)
// R3 architecture: S never hits HBM.
//  - gemm_topk: f16 MFMA GEMM; epilogue extracts per (row, 128-col block) the
//    block-local row max and <=8 candidates with s >= localmax - 15/beta
//    (global winners always satisfy this since globalmax >= localmax).
//    Candidate logits stored fp32 (removes R2's f16-S quantization error).
//  - topk_gather: per row, scan 128x8 candidate slots; softmax l computed over
//    candidates only (omitted mass <= N*3e-7 ~ 5e-3 relative -> ~0.015 abs err);
//    sparse weighted gather of V rows.
//  - LDS swizzle g(R) = ((R>>1)^(R>>3))&3: distinct bank-quads for contiguous-8
//    AND stride-8 lane groups (R2's (R>>1)&3 left 4-way stride-8 collisions).

typedef float    f32x4  __attribute__((ext_vector_type(4)));
typedef float    f32x16 __attribute__((ext_vector_type(16)));
typedef _Float16 f16x8  __attribute__((ext_vector_type(8)));
typedef _Float16 f16x4  __attribute__((ext_vector_type(4)));

#define LOG2E 1.44269504088896340736f
#define CAP 8          // candidate slots per (row, nblock)
#define SELMAX 256     // selection capacity in gather kernel

__device__ __forceinline__ void lds_load16(const void* g, void* l) {
    __builtin_amdgcn_global_load_lds(
        (__attribute__((address_space(1))) void*)(uintptr_t)g,
        (__attribute__((address_space(3))) void*)l,
        16, 0, 0);
}

__global__ void convert_f32_f16(const float* __restrict__ a, _Float16* __restrict__ o, long n4) {
    long i = (long)blockIdx.x * blockDim.x + threadIdx.x;
    if (i < n4) {
        f32x4 f = ((const f32x4*)a)[i];
        ((f16x4*)o)[i] = __builtin_convertvector(f, f16x4);
    }
}

__device__ __forceinline__ int swz_g(int R) { return ((R >> 1) ^ (R >> 3)) & 3; }

// LDS offset (halves) of 16B chunk holding (tile-row R, k-chunk c)
__device__ __forceinline__ int lds_off(int R, int c) {
    return (R >> 4) * 512 + (R & 15) * 32 + (((c + swz_g(R)) & 3) * 8);
}

// A:[M,K] f16 rm, Bm:[N,K] f16 rm. grid (N/128, M/128), block 256.
// Epilogue: per-row candidate extraction (no C write).
__global__ __launch_bounds__(256) void gemm_topk(
    const _Float16* __restrict__ A,
    const _Float16* __restrict__ Bm,
    int*   __restrict__ cnt_g,    // [M, NB]
    int*   __restrict__ cidx_g,   // [M, NB, CAP]
    float* __restrict__ cval_g,   // [M, NB, CAP]
    const float* __restrict__ beta_p,
    int N, int K)
{
    __shared__ _Float16 As[128 * 32];
    __shared__ _Float16 Bs[128 * 32];
    __shared__ float wred[2][128];
    __shared__ int   cntl[128];

    const int tid  = threadIdx.x;
    const int lane = tid & 63;
    const int wave = tid >> 6;
    const int wm = wave >> 1;
    const int wn = wave & 1;
    const int NB = gridDim.x;
    const long bm = (long)blockIdx.y * 128;
    const long bn = (long)blockIdx.x * 128;
    const float thr_off = 15.0f / beta_p[0];   // raw-logit units

    // staging: lane l -> LDS position (prow, pcol=l&3); fetch global chunk
    // c = (pcol - g(prow)) & 3 so that swizzled layout is lane-contiguous.
    const int srow  = lane >> 2;
    const int prow0 = wave * 32 + srow;
    const int prow1 = prow0 + 16;
    const int c0 = (((lane & 3) - swz_g(prow0)) & 3) * 8;
    const int c1 = (((lane & 3) - swz_g(prow1)) & 3) * 8;

    const _Float16* Ag0 = A + (bm + prow0) * (long)K + c0;
    const _Float16* Ag1 = A + (bm + prow1) * (long)K + c1;
    const _Float16* Bg0 = Bm + (bn + prow0) * (long)K + c0;
    const _Float16* Bg1 = Bm + (bn + prow1) * (long)K + c1;
    _Float16* As0 = &As[(wave * 32) * 32];
    _Float16* As1 = &As[(wave * 32 + 16) * 32];
    _Float16* Bs0 = &Bs[(wave * 32) * 32];
    _Float16* Bs1 = &Bs[(wave * 32 + 16) * 32];

    const int r32 = lane & 31;
    const int hi  = lane >> 5;
    int aoff[2][2], boff[2][2];
#pragma unroll
    for (int i = 0; i < 2; ++i)
#pragma unroll
        for (int s = 0; s < 2; ++s) {
            aoff[i][s] = lds_off(wm * 64 + i * 32 + r32, s * 2 + hi);
            boff[i][s] = lds_off(wn * 64 + i * 32 + r32, s * 2 + hi);
        }

    f32x16 acc[2][2] = {};

    for (int k0 = 0; k0 < K; k0 += 32) {
        lds_load16(Ag0 + k0, As0);
        lds_load16(Ag1 + k0, As1);
        lds_load16(Bg0 + k0, Bs0);
        lds_load16(Bg1 + k0, Bs1);
        __syncthreads();
#pragma unroll
        for (int s = 0; s < 2; ++s) {
            f16x8 af[2], bf[2];
#pragma unroll
            for (int i = 0; i < 2; ++i) af[i] = *(const f16x8*)&As[aoff[i][s]];
#pragma unroll
            for (int j = 0; j < 2; ++j) bf[j] = *(const f16x8*)&Bs[boff[j][s]];
#pragma unroll
            for (int i = 0; i < 2; ++i)
#pragma unroll
                for (int j = 0; j < 2; ++j)
                    acc[i][j] = __builtin_amdgcn_mfma_f32_32x32x16_f16(af[i], bf[j], acc[i][j], 0, 0, 0);
        }
        __syncthreads();
    }

    // ---- epilogue: candidate extraction ----
    // acc row = wm*64 + i*32 + rr, rr = (reg&3)+8*(reg>>2)+4*hi; col = wn*64 + j*32 + r32
    if (tid < 128) cntl[tid] = 0;

#pragma unroll
    for (int i = 0; i < 2; ++i) {
        float rmax[16];
#pragma unroll
        for (int reg = 0; reg < 16; ++reg)
            rmax[reg] = fmaxf(acc[i][0][reg], acc[i][1][reg]);
#pragma unroll
        for (int off = 1; off <= 16; off <<= 1)
#pragma unroll
            for (int reg = 0; reg < 16; ++reg)
                rmax[reg] = fmaxf(rmax[reg], __shfl_xor(rmax[reg], off));
        if (r32 == 0) {
#pragma unroll
            for (int reg = 0; reg < 16; ++reg) {
                const int rr = (reg & 3) + 8 * (reg >> 2) + 4 * hi;
                wred[wn][wm * 64 + i * 32 + rr] = rmax[reg];
            }
        }
    }
    __syncthreads();

#pragma unroll
    for (int i = 0; i < 2; ++i)
#pragma unroll
        for (int reg = 0; reg < 16; ++reg) {
            const int rr = (reg & 3) + 8 * (reg >> 2) + 4 * hi;
            const int rl = wm * 64 + i * 32 + rr;
            const float rm = fmaxf(wred[0][rl], wred[1][rl]) - thr_off;
#pragma unroll
            for (int j = 0; j < 2; ++j) {
                const float v = acc[i][j][reg];
                if (v >= rm) {
                    int p = atomicAdd(&cntl[rl], 1);
                    if (p < CAP) {
                        const size_t slot = ((size_t)(bm + rl) * NB + blockIdx.x) * CAP + p;
                        cidx_g[slot] = (int)(bn + wn * 64 + j * 32 + r32);
                        cval_g[slot] = v;
                    }
                }
            }
        }
    __syncthreads();
    if (tid < 128) {
        int c = cntl[tid];
        cnt_g[(size_t)(bm + tid) * NB + blockIdx.x] = c > CAP ? CAP : c;
    }
}

// One block (256 thr) per row: merge candidates, softmax over them, gather V.
__global__ __launch_bounds__(256) void topk_gather(
    const int*   __restrict__ cnt_g,
    const int*   __restrict__ cidx_g,
    const float* __restrict__ cval_g,
    const float* __restrict__ V,
    const float* __restrict__ X,
    float* __restrict__ Out,
    const float* __restrict__ beta_p,
    const float* __restrict__ alpha_p,
    int NB, int D)
{
    const int row  = blockIdx.x;
    const int tid  = threadIdx.x;
    const int lane = tid & 63;
    const int wave = tid >> 6;
    const float beta  = beta_p[0];
    const float alpha = alpha_p[0];

    __shared__ float redm[4];
    __shared__ float redl[4];
    __shared__ int   cs;
    __shared__ int   sel_idx[SELMAX + 4];
    __shared__ float sel_w[SELMAX + 4];

    int   myc = 0;
    int   idxs[8];
    float vb[8];
    if (tid < NB) {
        myc = cnt_g[(size_t)row * NB + tid];
        const int4*  ip = (const int4*) (cidx_g + ((size_t)row * NB + tid) * CAP);
        const f32x4* vp = (const f32x4*)(cval_g + ((size_t)row * NB + tid) * CAP);
        int4 a = ip[0], b = ip[1];
        f32x4 c = vp[0], d = vp[1];
        idxs[0]=a.x; idxs[1]=a.y; idxs[2]=a.z; idxs[3]=a.w;
        idxs[4]=b.x; idxs[5]=b.y; idxs[6]=b.z; idxs[7]=b.w;
        vb[0]=c[0]; vb[1]=c[1]; vb[2]=c[2]; vb[3]=c[3];
        vb[4]=d[0]; vb[5]=d[1]; vb[6]=d[2]; vb[7]=d[3];
    }
#pragma unroll
    for (int k = 0; k < 8; ++k) vb[k] = (k < myc) ? vb[k] * beta : -1e30f;

    float m = -1e30f;
#pragma unroll
    for (int k = 0; k < 8; ++k) m = fmaxf(m, vb[k]);
#pragma unroll
    for (int off = 32; off; off >>= 1) m = fmaxf(m, __shfl_xor(m, off));
    if (lane == 0) redm[wave] = m;
    if (tid == 0) cs = 0;
    __syncthreads();
    m = fmaxf(fmaxf(redm[0], redm[1]), fmaxf(redm[2], redm[3]));

    float e[8];
    float l = 0.f;
#pragma unroll
    for (int k = 0; k < 8; ++k) { e[k] = exp2f((vb[k] - m) * LOG2E); l += e[k]; }
#pragma unroll
    for (int off = 32; off; off >>= 1) l += __shfl_xor(l, off);
    if (lane == 0) redl[wave] = l;
    __syncthreads();
    l = redl[0] + redl[1] + redl[2] + redl[3];

#pragma unroll
    for (int k = 0; k < 8; ++k)
        if (k < myc && e[k] >= 3.0e-7f) {
            int p = atomicAdd(&cs, 1);
            if (p < SELMAX) { sel_idx[p] = idxs[k]; sel_w[p] = e[k]; }
        }
    __syncthreads();
    int ns = cs > SELMAX ? SELMAX : cs;
    if (tid < 4) { sel_idx[ns + tid] = sel_idx[0]; sel_w[ns + tid] = 0.f; }
    __syncthreads();

    const float wsc = alpha / l;
    const int col = tid * 4;
    f32x4 a0 = {0,0,0,0}, a1 = {0,0,0,0}, a2 = {0,0,0,0}, a3 = {0,0,0,0};
    const int ns4 = (ns + 3) & ~3;
    for (int i = 0; i < ns4; i += 4) {
        const f32x4 t0 = *(const f32x4*)(V + (size_t)sel_idx[i]     * D + col);
        const f32x4 t1 = *(const f32x4*)(V + (size_t)sel_idx[i + 1] * D + col);
        const f32x4 t2 = *(const f32x4*)(V + (size_t)sel_idx[i + 2] * D + col);
        const f32x4 t3 = *(const f32x4*)(V + (size_t)sel_idx[i + 3] * D + col);
        a0 += (sel_w[i]     * wsc) * t0;
        a1 += (sel_w[i + 1] * wsc) * t1;
        a2 += (sel_w[i + 2] * wsc) * t2;
        a3 += (sel_w[i + 3] * wsc) * t3;
    }
    const f32x4 xr = ((const f32x4*)(X + (size_t)row * D))[tid];
    ((f32x4*)(Out + (size_t)row * D))[tid] = xr + (a0 + a1) + (a2 + a3);
}

extern "C" void kernel_launch(void* const* d_in, const int* in_sizes, int n_in,
                              void* d_out, int out_size, void* d_ws, size_t ws_size,
                              hipStream_t stream) {
    const float* x     = (const float*)d_in[0];
    const float* kimg  = (const float*)d_in[1];
    const float* vtxt  = (const float*)d_in[2];
    const float* beta  = (const float*)d_in[3];
    const float* alpha = (const float*)d_in[4];
    float* out = (float*)d_out;

    const int D = 1024;
    const int B = in_sizes[0] / D;   // 4096
    const int N = in_sizes[1] / D;   // 16384
    const int NB = N / 128;          // 128

    char* ws = (char*)d_ws;
    _Float16* x16 = (_Float16*)ws;
    _Float16* k16 = (_Float16*)(ws + (size_t)B * D * 2);
    char* p = ws + (size_t)B * D * 2 + (size_t)N * D * 2;
    int*   cnt_g  = (int*)p;              p += (size_t)B * NB * 4;
    int*   cidx_g = (int*)p;              p += (size_t)B * NB * CAP * 4;
    float* cval_g = (float*)p;

    {
        long nx4 = (long)B * D / 4;
        long nk4 = (long)N * D / 4;
        convert_f32_f16<<<(unsigned)((nk4 + 255) / 256), 256, 0, stream>>>(kimg, k16, nk4);
        convert_f32_f16<<<(unsigned)((nx4 + 255) / 256), 256, 0, stream>>>(x, x16, nx4);
    }

    dim3 g1((unsigned)NB, (unsigned)(B / 128), 1);
    gemm_topk<<<g1, 256, 0, stream>>>(x16, k16, cnt_g, cidx_g, cval_g, beta, N, D);

    topk_gather<<<(unsigned)B, 256, 0, stream>>>(
        cnt_g, cidx_g, cval_g, vtxt, x, out, beta, alpha, NB, D);
}

// Round 4
// 390.872 us; speedup vs baseline: 1.1496x; 1.1496x over previous
//
#include <hip/hip_runtime.h>

// out = x + alpha * softmax(beta * x @ K^T) @ V   (B=4096, N=16384, D=1024, fp32)
// R4: de-fused pipeline (R3's in-GEMM epilogue cost +120us; see journal).
//   1) convert x,K -> f16
//   2) gemm_bt_f16: R2's proven kernel verbatim (189us) -> S f16 [R,N]
//   3) scan_rows: 1 block per quarter-row; exact partial max + partial sumexp
//      (fp32) + candidates t >= pmax-15 (CAP 24; overflowing partitions are
//      provably junk: their global weights ~e^-45)
//   4) finalize_gather: merge 4 partials/row (exact l), select w>=3e-7,
//      weighted sparse gather of V rows, fused residual add.

typedef float    f32x4  __attribute__((ext_vector_type(4)));
typedef float    f32x16 __attribute__((ext_vector_type(16)));
typedef _Float16 f16x8  __attribute__((ext_vector_type(8)));
typedef _Float16 f16x4  __attribute__((ext_vector_type(4)));

#define LOG2E 1.44269504088896340736f
#define PCAP 24
#define SELMAX 128

__device__ __forceinline__ void lds_load16(const void* g, void* l) {
    __builtin_amdgcn_global_load_lds(
        (__attribute__((address_space(1))) void*)(uintptr_t)g,
        (__attribute__((address_space(3))) void*)l,
        16, 0, 0);
}

__global__ void convert_f32_f16(const float* __restrict__ a, _Float16* __restrict__ o, long n4) {
    long i = (long)blockIdx.x * blockDim.x + threadIdx.x;
    if (i < n4) {
        f32x4 f = ((const f32x4*)a)[i];
        ((f16x4*)o)[i] = __builtin_convertvector(f, f16x4);
    }
}

// ---- R2's GEMM, verbatim (proven 189us) ----
__device__ __forceinline__ int lds_off(int R, int c) {
    int r = R & 15;
    return (R >> 4) * 512 + r * 32 + (((c + (r >> 1)) & 3) * 8);
}

__global__ __launch_bounds__(256) void gemm_bt_f16(
    const _Float16* __restrict__ A,
    const _Float16* __restrict__ Bm,
    _Float16* __restrict__ C,
    int N, int K)
{
    __shared__ _Float16 As[128 * 32];
    __shared__ _Float16 Bs[128 * 32];
    const int tid  = threadIdx.x;
    const int lane = tid & 63;
    const int wave = tid >> 6;
    const int wm = wave >> 1;
    const int wn = wave & 1;
    const long bm = (long)blockIdx.y * 128;
    const long bn = (long)blockIdx.x * 128;

    const int srow = lane >> 2;
    const int scol = (((lane & 3) - (srow >> 1)) & 3) * 8;

    const _Float16* Ag0 = A + (bm + wave * 32 + srow) * (long)K + scol;
    const _Float16* Ag1 = Ag0 + 16L * K;
    const _Float16* Bg0 = Bm + (bn + wave * 32 + srow) * (long)K + scol;
    const _Float16* Bg1 = Bg0 + 16L * K;
    _Float16* As0 = &As[(wave * 32) * 32];
    _Float16* As1 = &As[(wave * 32 + 16) * 32];
    _Float16* Bs0 = &Bs[(wave * 32) * 32];
    _Float16* Bs1 = &Bs[(wave * 32 + 16) * 32];

    const int r32 = lane & 31;
    const int hi  = lane >> 5;
    int aoff[2][2], boff[2][2];
#pragma unroll
    for (int i = 0; i < 2; ++i)
#pragma unroll
        for (int s = 0; s < 2; ++s) {
            aoff[i][s] = lds_off(wm * 64 + i * 32 + r32, s * 2 + hi);
            boff[i][s] = lds_off(wn * 64 + i * 32 + r32, s * 2 + hi);
        }

    f32x16 acc[2][2] = {};

    for (int k0 = 0; k0 < K; k0 += 32) {
        lds_load16(Ag0 + k0, As0);
        lds_load16(Ag1 + k0, As1);
        lds_load16(Bg0 + k0, Bs0);
        lds_load16(Bg1 + k0, Bs1);
        __syncthreads();
#pragma unroll
        for (int s = 0; s < 2; ++s) {
            f16x8 af[2], bf[2];
#pragma unroll
            for (int i = 0; i < 2; ++i) af[i] = *(const f16x8*)&As[aoff[i][s]];
#pragma unroll
            for (int j = 0; j < 2; ++j) bf[j] = *(const f16x8*)&Bs[boff[j][s]];
#pragma unroll
            for (int i = 0; i < 2; ++i)
#pragma unroll
                for (int j = 0; j < 2; ++j)
                    acc[i][j] = __builtin_amdgcn_mfma_f32_32x32x16_f16(af[i], bf[j], acc[i][j], 0, 0, 0);
        }
        __syncthreads();
    }

    const int ccol = lane & 31;
#pragma unroll
    for (int i = 0; i < 2; ++i) {
#pragma unroll
        for (int j = 0; j < 2; ++j) {
            const long rb = bm + wm * 64 + i * 32;
            const long cb = bn + wn * 64 + j * 32 + ccol;
#pragma unroll
            for (int reg = 0; reg < 16; ++reg) {
                const int rr = (reg & 3) + 8 * (reg >> 2) + 4 * hi;
                C[(rb + rr) * (long)N + cb] = (_Float16)acc[i][j][reg];
            }
        }
    }
}

// ---- streaming scan: 1 block per quarter-row ----
__global__ __launch_bounds__(256) void scan_rows(
    const _Float16* __restrict__ S,   // [Rc, N]
    float* __restrict__ pm,           // [Rc,4]
    float* __restrict__ pl,           // [Rc,4]
    int*   __restrict__ pcnt,         // [Rc,4]
    int*   __restrict__ pidx,         // [Rc,4,PCAP]
    float* __restrict__ pval,         // [Rc,4,PCAP]
    const float* __restrict__ beta_p, int N)
{
    const int row  = blockIdx.x >> 2;
    const int part = blockIdx.x & 3;
    const int tid  = threadIdx.x;
    const int lane = tid & 63;
    const int wave = tid >> 6;
    const int Q = N >> 2;   // 4096
    const float beta = beta_p[0];

    __shared__ float redm[4], redl[4];
    __shared__ int cnt;

    const f16x8* s8 = (const f16x8*)(S + (size_t)row * N + (size_t)part * Q);
    f16x8 h0 = s8[tid];
    f16x8 h1 = s8[tid + 256];
    float t[16];
#pragma unroll
    for (int c = 0; c < 8; ++c) { t[c] = (float)h0[c] * beta; t[8 + c] = (float)h1[c] * beta; }

    float m = t[0];
#pragma unroll
    for (int c = 1; c < 16; ++c) m = fmaxf(m, t[c]);
#pragma unroll
    for (int off = 32; off; off >>= 1) m = fmaxf(m, __shfl_xor(m, off));
    if (lane == 0) redm[wave] = m;
    if (tid == 0) cnt = 0;
    __syncthreads();
    m = fmaxf(fmaxf(redm[0], redm[1]), fmaxf(redm[2], redm[3]));

    float l = 0.f;
#pragma unroll
    for (int c = 0; c < 16; ++c) l += exp2f((t[c] - m) * LOG2E);
#pragma unroll
    for (int off = 32; off; off >>= 1) l += __shfl_xor(l, off);
    if (lane == 0) redl[wave] = l;
    __syncthreads();

    const float thr = m - 15.0f;
#pragma unroll
    for (int c = 0; c < 16; ++c) {
        if (t[c] >= thr) {
            int p = atomicAdd(&cnt, 1);
            if (p < PCAP) {
                const int nloc = (c < 8) ? (tid * 8 + c) : ((tid + 256) * 8 + (c - 8));
                const size_t slot = ((size_t)row * 4 + part) * PCAP + p;
                pidx[slot] = part * Q + nloc;
                pval[slot] = t[c];
            }
        }
    }
    __syncthreads();
    if (tid == 0) {
        int c = cnt; if (c > PCAP) c = PCAP;
        const size_t o = (size_t)row * 4 + part;
        pm[o] = m;
        pl[o] = redl[0] + redl[1] + redl[2] + redl[3];
        pcnt[o] = c;
    }
}

// ---- per-row finalize + sparse V gather ----
__global__ __launch_bounds__(256) void finalize_gather(
    const float* __restrict__ pm, const float* __restrict__ pl, const int* __restrict__ pcnt,
    const int* __restrict__ pidx, const float* __restrict__ pval,
    const float* __restrict__ V, const float* __restrict__ X, float* __restrict__ Out,
    const float* __restrict__ alpha_p, int D)
{
    const int row = blockIdx.x;
    const int tid = threadIdx.x;
    const float alpha = alpha_p[0];

    __shared__ float mm[4], llv[4];
    __shared__ int cc[4];
    __shared__ int cs;
    __shared__ int   sel_idx[SELMAX + 4];
    __shared__ float sel_w[SELMAX + 4];

    if (tid < 4) { mm[tid] = pm[row * 4 + tid]; llv[tid] = pl[row * 4 + tid]; cc[tid] = pcnt[row * 4 + tid]; }
    if (tid == 0) cs = 0;
    __syncthreads();
    const float m = fmaxf(fmaxf(mm[0], mm[1]), fmaxf(mm[2], mm[3]));
    const float l = llv[0] * exp2f((mm[0] - m) * LOG2E) + llv[1] * exp2f((mm[1] - m) * LOG2E)
                  + llv[2] * exp2f((mm[2] - m) * LOG2E) + llv[3] * exp2f((mm[3] - m) * LOG2E);

    if (tid < 4 * PCAP) {
        const int p = tid / PCAP, k = tid % PCAP;
        if (k < cc[p]) {
            const size_t slot = ((size_t)row * 4 + p) * PCAP + k;
            const float w = exp2f((pval[slot] - m) * LOG2E);
            if (w >= 3.0e-7f) {
                int q = atomicAdd(&cs, 1);
                if (q < SELMAX) { sel_idx[q] = pidx[slot]; sel_w[q] = w; }
            }
        }
    }
    __syncthreads();
    int ns = cs > SELMAX ? SELMAX : cs;
    if (tid < 4) { sel_idx[ns + tid] = ns ? sel_idx[0] : 0; sel_w[ns + tid] = 0.f; }
    __syncthreads();

    const float wsc = alpha / l;
    const int col = tid * 4;
    f32x4 a0 = {0,0,0,0}, a1 = {0,0,0,0}, a2 = {0,0,0,0}, a3 = {0,0,0,0};
    const int ns4 = (ns + 3) & ~3;
    for (int i = 0; i < ns4; i += 4) {
        const f32x4 t0 = *(const f32x4*)(V + (size_t)sel_idx[i]     * D + col);
        const f32x4 t1 = *(const f32x4*)(V + (size_t)sel_idx[i + 1] * D + col);
        const f32x4 t2 = *(const f32x4*)(V + (size_t)sel_idx[i + 2] * D + col);
        const f32x4 t3 = *(const f32x4*)(V + (size_t)sel_idx[i + 3] * D + col);
        a0 += (sel_w[i]     * wsc) * t0;
        a1 += (sel_w[i + 1] * wsc) * t1;
        a2 += (sel_w[i + 2] * wsc) * t2;
        a3 += (sel_w[i + 3] * wsc) * t3;
    }
    const f32x4 xr = ((const f32x4*)(X + (size_t)row * D))[tid];
    ((f32x4*)(Out + (size_t)row * D))[tid] = xr + (a0 + a1) + (a2 + a3);
}

extern "C" void kernel_launch(void* const* d_in, const int* in_sizes, int n_in,
                              void* d_out, int out_size, void* d_ws, size_t ws_size,
                              hipStream_t stream) {
    const float* x     = (const float*)d_in[0];
    const float* kimg  = (const float*)d_in[1];
    const float* vtxt  = (const float*)d_in[2];
    const float* beta  = (const float*)d_in[3];
    const float* alpha = (const float*)d_in[4];
    float* out = (float*)d_out;

    const int D = 1024;
    const int B = in_sizes[0] / D;   // 4096
    const int N = in_sizes[1] / D;   // 16384

    char* ws = (char*)d_ws;
    _Float16* x16 = (_Float16*)ws;
    _Float16* k16 = (_Float16*)(ws + (size_t)B * D * 2);
    const size_t fixed = (size_t)B * D * 2 + (size_t)N * D * 2;

    // per-row ws: S f16 (N*2) + pm/pl/pcnt (48) + pidx/pval (4*PCAP*8)
    const size_t perrow = (size_t)N * 2 + 48 + (size_t)4 * PCAP * 8;
    size_t avail = ws_size > fixed ? ws_size - fixed : 0;
    long Rl = (long)(avail / perrow);
    Rl &= ~127L;
    int R = (int)(Rl > B ? B : Rl);
    if (R < 128) R = 128;

    char* p = ws + fixed;
    _Float16* S  = (_Float16*)p;  p += (size_t)R * N * 2;
    float* pm    = (float*)p;     p += (size_t)R * 16;
    float* pl    = (float*)p;     p += (size_t)R * 16;
    int*   pcnt  = (int*)p;       p += (size_t)R * 16;
    int*   pidx  = (int*)p;       p += (size_t)R * 4 * PCAP * 4;
    float* pval  = (float*)p;

    {
        long nx4 = (long)B * D / 4;
        long nk4 = (long)N * D / 4;
        convert_f32_f16<<<(unsigned)((nk4 + 255) / 256), 256, 0, stream>>>(kimg, k16, nk4);
        convert_f32_f16<<<(unsigned)((nx4 + 255) / 256), 256, 0, stream>>>(x, x16, nx4);
    }

    for (int r0 = 0; r0 < B; r0 += R) {
        int Rc = B - r0; if (Rc > R) Rc = R;
        dim3 g1((unsigned)(N / 128), (unsigned)(Rc / 128), 1);
        gemm_bt_f16<<<g1, 256, 0, stream>>>(x16 + (size_t)r0 * D, k16, S, N, D);
        scan_rows<<<(unsigned)(Rc * 4), 256, 0, stream>>>(S, pm, pl, pcnt, pidx, pval, beta, N);
        finalize_gather<<<(unsigned)Rc, 256, 0, stream>>>(
            pm, pl, pcnt, pidx, pval, vtxt, x + (size_t)r0 * D, out + (size_t)r0 * D, alpha, D);
    }
}